// Round 2
// baseline (187.955 us; speedup 1.0000x reference)
//
#include <hip/hip_runtime.h>

// ADI diffusion B=16, C=8, S=128, 10 steps. Round 11: resubmit of round-10
// occupancy split (previous bench died on container acquire, not kernel).
// Band height 8 -> 4 rows (grid 256 -> 512 blocks), LDS restructured into
// three 32-row compact regions (49.5 KB non-head) -> 2 blocks/CU = 16
// waves/CU (was 1 block/CU = 8 waves). Numerics identical: Jacobi-2 radius
// is 2, so 8-in/4-out h-window == 12-in/8-out per output row.
// Head dispatch keeps an extra 64-row staging band (82.5 KB, 1 block/CU).

constexpr int S_ = 128;
constexpr int RS = 129;             // padded LDS row stride (bank = (row+col)%32)
constexpr float EPSF = 1e-6f;

// 32-row regions (floats):
constexpr int OFF_X  = 0;           // Y-out compact / mix-out / X1+X2 input
constexpr int OFF_C  = 32 * RS;     // x-direction coeff co
constexpr int OFF_B  = 64 * RS;     // xo between X1 and mix
constexpr int OFF_HA = 96 * RS;     // head only: x@0 output band (64 rows)

template <int N>
__device__ __forceinline__ void jrunN(const float (&e)[N], const float (&g)[N],
                                      float (&o)[N - 4]) {
    // Jacobi-2 == fixed 5-point formula, stencil radius 2 per output.
    float x1[N];
    #pragma unroll
    for (int i = 1; i <= N - 2; ++i) x1[i] = fmaf(g[i], e[i - 1] + e[i + 1], e[i]);
    #pragma unroll
    for (int i = 2; i <= N - 3; ++i) o[i - 2] = fmaf(g[i], x1[i - 1] + x1[i + 1], e[i]);
}

template <bool HEAD, bool TAILMIX>
__global__ __launch_bounds__(512, 4) void step_kernel(
    const float* __restrict__ usrc, float* __restrict__ udst,
    const float* __restrict__ ab, const float* __restrict__ atc,
    const float* __restrict__ bbeta, const float* __restrict__ btc,
    const float* __restrict__ cm, float t_y, float t_x)
{
    constexpr int POOL = HEAD ? 160 * RS : 96 * RS;
    __shared__ float sP[POOL];
    const int tid = threadIdx.x;
    const int b   = blockIdx.x >> 5;          // 16 batches
    const int h0  = (blockIdx.x & 31) << 2;   // 32 chunks of 4 rows

    if (HEAD) {
        // load 8-row band (gh = h0-2 .. h0+5) into staging rows 0..63
        #pragma unroll
        for (int m = 0; m < 2; ++m) {
            const int col = tid + 512 * m;
            const int c = col >> 7, w = col & 127;
            #pragma unroll
            for (int hh = 0; hh < 8; ++hh) {
                const int gh = h0 - 2 + hh;
                float v = 0.f;
                if (gh >= 0 && gh < S_) v = usrc[((b * 8 + c) * S_ + gh) * S_ + w];
                sP[(c * 8 + hh) * RS + w] = v;
            }
        }
        __syncthreads();
        // channel mix in place (each (hh,w) point owned by one thread)
        {
            float M[64];
            #pragma unroll
            for (int i = 0; i < 64; ++i) M[i] = cm[i];
            #pragma unroll
            for (int m = 0; m < 2; ++m) {
                const int p = tid + 512 * m;
                const int hh = p >> 7, w = p & 127;
                float v[8], o[8];
                #pragma unroll
                for (int c = 0; c < 8; ++c) v[c] = sP[(c * 8 + hh) * RS + w];
                #pragma unroll
                for (int dd = 0; dd < 8; ++dd) {
                    float a = 0.f;
                    #pragma unroll
                    for (int c = 0; c < 8; ++c) a = fmaf(M[dd * 8 + c], v[c], a);
                    o[dd] = a;
                }
                #pragma unroll
                for (int c = 0; c < 8; ++c) sP[(c * 8 + hh) * RS + w] = o[c];
            }
        }
        __syncthreads();
        // x@0 on 64 rows x 16 runs (alpha = clip(ab), t=0); write -> OFF_HA
        #pragma unroll
        for (int m = 0; m < 2; ++m) {
            const int run = tid + 512 * m;
            const int r64 = run & 63;
            const int wr  = run >> 6;
            const int c = r64 >> 3, hh = r64 & 7;
            const int gh = h0 - 2 + hh;
            const int w0 = wr * 8;
            const bool rowin = (gh >= 0 && gh < S_);
            float e[12], g[12];
            #pragma unroll
            for (int j = 0; j < 12; ++j) {
                const int wj = w0 - 2 + j;
                const bool win = (wj >= 0 && wj < S_);
                const float dv = win ? sP[r64 * RS + wj] : 0.f;
                float co = 0.f;
                if (rowin && win) {
                    float al = ab[(c * S_ + gh) * S_ + wj];
                    al = fminf(fmaxf(al, EPSF), 10.f);
                    co = al * 0.0005f;
                }
                const float nb = (wj == 0 || wj == S_ - 1) ? 1.f : 2.f;
                const float rb = __builtin_amdgcn_rcpf(fmaf(nb, co, 1.f) + EPSF);
                e[j] = rb * dv; g[j] = rb * co;
            }
            float o[8]; jrunN<12>(e, g, o);
            #pragma unroll
            for (int i = 0; i < 8; ++i) sP[OFF_HA + r64 * RS + w0 + i] = o[i];
        }
        __syncthreads();
    }

    // ---- Y stage: 1024 (c,w) columns, 2/thread; 8-in/4-out along h.
    #pragma unroll
    for (int m = 0; m < 2; ++m) {
        const int col = tid + 512 * m;
        const int c = col >> 7, w = col & 127;
        float e[8], g[8];
        #pragma unroll
        for (int hh = 0; hh < 8; ++hh) {
            const int gh = h0 - 2 + hh;
            const bool inr = (gh >= 0 && gh < S_);
            const int ghc = inr ? gh : 0;
            float dv;
            if (HEAD) dv = sP[OFF_HA + (c * 8 + hh) * RS + w];
            else      dv = inr ? usrc[((b * 8 + c) * S_ + ghc) * S_ + w] : 0.f;
            const int gc = (c * S_ + ghc) * S_ + w;
            float be = fmaf(btc[gc], t_y, bbeta[gc]);
            be = fminf(fmaxf(be, EPSF), 10.f);
            const float co = inr ? be * 0.001f : 0.f;
            const float nb = (gh == 0 || gh == S_ - 1) ? 1.f : 2.f;
            const float rb = __builtin_amdgcn_rcpf(fmaf(nb, co, 1.f) + EPSF);
            e[hh] = rb * dv; g[hh] = rb * co;
        }
        float o[4]; jrunN<8>(e, g, o);
        #pragma unroll
        for (int i = 0; i < 4; ++i) sP[OFF_X + (c * 4 + i) * RS + w] = o[i];
    }
    // x-coeff into C (coalesced point layout, 32 rows)
    #pragma unroll
    for (int m = 0; m < 8; ++m) {
        const int p = tid + 512 * m;
        const int r = p >> 7, w = p & 127;
        const int c = r >> 2, ho = r & 3;
        const int gc = (c * S_ + h0 + ho) * S_ + w;
        float al = fmaf(atc[gc], t_x, ab[gc]);
        al = fminf(fmaxf(al, EPSF), 10.f);
        sP[OFF_C + r * RS + w] = al * 0.0005f;
    }
    __syncthreads();

    // ---- X1: 32 rows x 16 runs, 1/thread (row-per-lane -> <=2 lanes/bank)
    const int r32 = tid & 31, wr = tid >> 5;
    const int w0 = wr * 8;
    float rbk[12], gk[12], xo[8];
    {
        float e[12];
        #pragma unroll
        for (int j = 0; j < 12; ++j) {
            const int wj = w0 - 2 + j;
            const bool win = (wj >= 0 && wj < S_);
            const float co = win ? sP[OFF_C + r32 * RS + wj] : 0.f;
            const float dv = win ? sP[OFF_X + r32 * RS + wj] : 0.f;
            const float nb = (wj == 0 || wj == S_ - 1) ? 1.f : 2.f;
            const float rb = __builtin_amdgcn_rcpf(fmaf(nb, co, 1.f) + EPSF);
            rbk[j] = rb; gk[j] = rb * co;
            e[j] = rb * dv;
        }
        jrunN<12>(e, gk, xo);
    }

    if (TAILMIX) {
        // park xo in B (disjoint region -> no extra barrier needed first)
        #pragma unroll
        for (int i = 0; i < 8; ++i) sP[OFF_B + r32 * RS + w0 + i] = xo[i];
        __syncthreads();
        // mix: 512 points, 1/thread; read B, write X
        {
            float M[64];
            #pragma unroll
            for (int i = 0; i < 64; ++i) M[i] = cm[i];
            const int ho = tid >> 7, w = tid & 127;
            float v[8], o[8];
            #pragma unroll
            for (int c = 0; c < 8; ++c) v[c] = sP[OFF_B + (c * 4 + ho) * RS + w];
            #pragma unroll
            for (int dd = 0; dd < 8; ++dd) {
                float a = 0.f;
                #pragma unroll
                for (int c = 0; c < 8; ++c) a = fmaf(M[dd * 8 + c], v[c], a);
                o[dd] = a;
            }
            #pragma unroll
            for (int c = 0; c < 8; ++c) sP[OFF_X + (c * 4 + ho) * RS + w] = o[c];
        }
        __syncthreads();
        // X2: same runs, same coeffs (same t)
        {
            const int c = r32 >> 2, ho = r32 & 3;
            float e[12];
            #pragma unroll
            for (int j = 0; j < 12; ++j) {
                const int wj = w0 - 2 + j;
                const bool win = (wj >= 0 && wj < S_);
                const float dv = win ? sP[OFF_X + r32 * RS + wj] : 0.f;
                e[j] = rbk[j] * dv;
            }
            float o[8]; jrunN<12>(e, gk, o);
            float4* dst4 = (float4*)&udst[((b * 8 + c) * S_ + h0 + ho) * S_ + w0];
            dst4[0] = make_float4(o[0], o[1], o[2], o[3]);
            dst4[1] = make_float4(o[4], o[5], o[6], o[7]);
        }
    } else {
        const int c = r32 >> 2, ho = r32 & 3;
        float4* dst4 = (float4*)&udst[((b * 8 + c) * S_ + h0 + ho) * S_ + w0];
        dst4[0] = make_float4(xo[0], xo[1], xo[2], xo[3]);
        dst4[1] = make_float4(xo[4], xo[5], xo[6], xo[7]);
    }
}

extern "C" void kernel_launch(void* const* d_in, const int* in_sizes, int n_in,
                              void* d_out, int out_size, void* d_ws, size_t ws_size,
                              hipStream_t stream) {
    const float* u_in = (const float*)d_in[0];
    const float* ab   = (const float*)d_in[1];
    const float* bbta = (const float*)d_in[2];
    const float* atc  = (const float*)d_in[3];
    const float* btc  = (const float*)d_in[4];
    const float* cm   = (const float*)d_in[5];
    float* uo = (float*)d_out;
    float* uw = (float*)d_ws;     // 8 MB ping buffer

    const dim3 g(512), blk(512);
    const float dt2 = 0.0005f;

    // k=0: head(mix|x@0) + y@0.5 + x@1|mix|x@1, pristine input -> ws
    step_kernel<true, true><<<g, blk, 0, stream>>>(u_in, uw, ab, atc, bbta, btc, cm,
                                                   1 * dt2, 2 * dt2);
    const float* src = uw; float* dst = uo;
    for (int k = 1; k <= 8; ++k) {
        step_kernel<false, true><<<g, blk, 0, stream>>>(src, dst, ab, atc, bbta, btc, cm,
                                                        (2 * k + 1) * dt2, (2 * k + 2) * dt2);
        const float* ns = dst; dst = (dst == uo) ? uw : uo; src = ns;
    }
    // k=9: y@9.5 + x@10 (no mix) -> d_out (parity: src=uw, dst=uo)
    step_kernel<false, false><<<g, blk, 0, stream>>>(src, dst, ab, atc, bbta, btc, cm,
                                                     19 * dt2, 20 * dt2);
}